// Round 4
// baseline (21.645 us; speedup 1.0000x reference)
//
#include <hip/hip_runtime.h>

// BKT: B=4096 students, T=512 timesteps, K=2048 skills.
// One block per student, one thread per timestep.
// Round-based propagation (R3, passed absmax 0) + packed-parameter gather:
// R3 == R1 in time (19 us) despite totally different replay structure ->
// common cost dominates. Theory: 4 scattered dword gathers/thread of the
// per-skill params serialize on L1 line throughput (~32 gather instrs x
// ~60 cy per block). Fix: pack (k0,t,g,s) into float4[K] in d_ws (prep
// kernel), one dwordx4 gather per thread. Also dropped resp_s staging
// (round scheme reads only the thread's own response).

#define BKT_B 4096
#define BKT_T 512
#define BKT_K 2048

__device__ __forceinline__ float bkt_update(float pL, float r, float ss,
                                            float gg, float tt) {
  float num, den;
  if (r > 0.5f) {            // correct response
    num = pL * (1.0f - ss);
    den = num + (1.0f - pL) * gg;
  } else {                   // incorrect response
    num = pL * ss;
    den = num + (1.0f - pL) * (1.0f - gg);
  }
  const float q = num / den; // Bayesian posterior
  return q + (1.0f - q) * tt;// learning transition
}

__global__ __launch_bounds__(256) void bkt_pack_params(
    const float* __restrict__ k0, const float* __restrict__ tp,
    const float* __restrict__ gp, const float* __restrict__ sp,
    float4* __restrict__ packed) {
  const int k = blockIdx.x * 256 + threadIdx.x;
  packed[k] = make_float4(k0[k], tp[k], gp[k], sp[k]);
}

template <bool PACKED>
__global__ __launch_bounds__(512) void bkt_kernel(
    const int* __restrict__ skills,
    const float* __restrict__ resp,
    const float* __restrict__ k0,
    const float* __restrict__ tp,
    const float* __restrict__ gp,
    const float* __restrict__ sp,
    const float4* __restrict__ packed,
    float* __restrict__ out) {
  __shared__ int   nxt_s[BKT_T];    // linked-list next (arbitrary order)
  __shared__ float post_s[BKT_T];   // posterior AFTER update at time t
  __shared__ int   head_s[BKT_K];   // per-skill list head
  __shared__ int   maxrank_s;

  const int b = blockIdx.x;
  const int t = threadIdx.x;
  const int base = b * BKT_T;

  const int sk = skills[base + t];       // coalesced
  const float rr = resp[base + t];       // coalesced (own response only)

  // single 16B scattered gather of all per-skill params
  float kk, tt, gg, ss;
  if (PACKED) {
    const float4 pr = packed[sk];
    kk = pr.x; tt = pr.y; gg = pr.z; ss = pr.w;
  } else {
    kk = k0[sk]; tt = tp[sk]; gg = gp[sk]; ss = sp[sk];
  }

  if (t == 0) maxrank_s = 0;
#pragma unroll
  for (int i = 0; i < BKT_K / BKT_T; ++i)
    head_s[t + i * BKT_T] = -1;
  __syncthreads();

  // build per-skill linked lists (order irrelevant)
  nxt_s[t] = atomicExch(&head_s[sk], t);
  __syncthreads();

  // single chain walk: prev = latest earlier same-skill touch, rank = count
  int prev = -1, rank = 0;
  for (int j = head_s[sk]; j >= 0; j = nxt_s[j]) {
    if (j < t) { ++rank; prev = max(prev, j); }
  }
  if (rank >= 1) atomicMax(&maxrank_s, rank);

  float pL = kk;                   // mastery BEFORE update at t (rank 0)

  if (rank == 0) post_s[t] = bkt_update(pL, rr, ss, gg, tt);
  __syncthreads();

  const int MR = maxrank_s;
  for (int rd = 1; rd <= MR; ++rd) {
    if (rank == rd) {
      pL = post_s[prev];
      post_s[t] = bkt_update(pL, rr, ss, gg, tt);
    }
    __syncthreads();
  }

  out[base + t] = pL;              // emit pre-update mastery
}

extern "C" void kernel_launch(void* const* d_in, const int* in_sizes, int n_in,
                              void* d_out, int out_size, void* d_ws, size_t ws_size,
                              hipStream_t stream) {
  const int*   skills = (const int*)d_in[0];
  const float* resp   = (const float*)d_in[1];
  const float* k0     = (const float*)d_in[2];
  const float* tp     = (const float*)d_in[3];
  const float* gp     = (const float*)d_in[4];
  const float* sp     = (const float*)d_in[5];
  float* out = (float*)d_out;

  if (ws_size >= BKT_K * sizeof(float4)) {
    float4* packed = (float4*)d_ws;
    bkt_pack_params<<<BKT_K / 256, 256, 0, stream>>>(k0, tp, gp, sp, packed);
    bkt_kernel<true><<<BKT_B, BKT_T, 0, stream>>>(skills, resp, k0, tp, gp,
                                                  sp, packed, out);
  } else {
    bkt_kernel<false><<<BKT_B, BKT_T, 0, stream>>>(skills, resp, k0, tp, gp,
                                                   sp, nullptr, out);
  }
}

// Round 5
// 19.002 us; speedup vs baseline: 1.1391x; 1.1391x over previous
//
#include <hip/hip_runtime.h>
#include <limits.h>

// BKT: B=4096 students, T=512 timesteps, K=2048 skills.
// R5: occupancy experiment. R1/R3/R4 (three different inner algorithms, all
// 512-thread blocks) tied at ~19 us -> shared bottleneck = only 4 blocks/CU
// in flight (8 waves/block, 32 waves/CU cap) to hide each block's long
// dependent-latency path. This version: 128-thread blocks (2 waves), 4
// timesteps/thread -> 13 blocks/CU (LDS-limited at 12.3 KB), 3.25x more
// independent latency streams. Min-extraction replay (R1 style, verified
// absmax 0): only 2 barriers, no per-round sync, no same-address atomics.

#define BKT_B 4096
#define BKT_T 512
#define BKT_K 2048
#define BLK   128
#define TPT   (BKT_T / BLK)   // 4 timesteps per thread

__global__ __launch_bounds__(BLK) void bkt_kernel(
    const int* __restrict__ skills,
    const float* __restrict__ resp,
    const float* __restrict__ k0,
    const float* __restrict__ tp,
    const float* __restrict__ gp,
    const float* __restrict__ sp,
    float* __restrict__ out) {
  __shared__ int   nxt_s[BKT_T];    // linked-list next (arbitrary order)
  __shared__ float resp_s[BKT_T];
  __shared__ int   head_s[BKT_K];   // per-skill list head

  const int b = blockIdx.x;
  const int base = b * BKT_T;
  const int tid = threadIdx.x;

  // init head table (16 writes/thread)
#pragma unroll
  for (int i = 0; i < BKT_K / BLK; ++i)
    head_s[tid + i * BLK] = -1;

  // stage this student's rows (coalesced), keep own skills in registers
  int sk[TPT];
#pragma unroll
  for (int u = 0; u < TPT; ++u) {
    const int t = tid + u * BLK;
    sk[u] = skills[base + t];
    resp_s[t] = resp[base + t];
  }
  __syncthreads();

  // build per-skill linked lists (order irrelevant)
#pragma unroll
  for (int u = 0; u < TPT; ++u) {
    const int t = tid + u * BLK;
    nxt_s[t] = atomicExch(&head_s[sk[u]], t);
  }
  __syncthreads();

  // replay each owned timestep's same-skill prefix from k0 (min-extraction)
#pragma unroll
  for (int u = 0; u < TPT; ++u) {
    const int t = tid + u * BLK;
    const int s_ = sk[u];
    const float ss = sp[s_];
    const float gg = gp[s_];
    const float tt = tp[s_];
    float p = k0[s_];                // mastery before any touch
    const int head = head_s[s_];
    int cur = -1;
    for (;;) {
      int best = INT_MAX;
      for (int j = head; j >= 0; j = nxt_s[j])
        if (j < t && j > cur) best = min(best, j);
      if (best == INT_MAX) break;
      const float r = resp_s[best];
      float num, den;
      if (r > 0.5f) {                // correct response
        num = p * (1.0f - ss);
        den = num + (1.0f - p) * gg;
      } else {                       // incorrect response
        num = p * ss;
        den = num + (1.0f - p) * (1.0f - gg);
      }
      const float q = num / den;     // Bayesian posterior
      p = q + (1.0f - q) * tt;       // learning transition
      cur = best;
    }
    out[base + t] = p;               // emit pre-update mastery
  }
}

extern "C" void kernel_launch(void* const* d_in, const int* in_sizes, int n_in,
                              void* d_out, int out_size, void* d_ws, size_t ws_size,
                              hipStream_t stream) {
  const int*   skills = (const int*)d_in[0];
  const float* resp   = (const float*)d_in[1];
  const float* k0     = (const float*)d_in[2];
  const float* tp     = (const float*)d_in[3];
  const float* gp     = (const float*)d_in[4];
  const float* sp     = (const float*)d_in[5];
  float* out = (float*)d_out;

  bkt_kernel<<<BKT_B, BLK, 0, stream>>>(skills, resp, k0, tp, gp, sp, out);
}

// Round 6
// 15.489 us; speedup vs baseline: 1.3974x; 1.2268x over previous
//
#include <hip/hip_runtime.h>
#include <limits.h>

// BKT: B=4096 students, T=512 timesteps, K=2048 skills.
// R6: lean discriminator. R1/R3/R5 (3 algorithms x 3 launch shapes) all tied
// at 19.0 us +/- 0.6% -> in-kernel structure exonerated piece by piece.
// This version removes every remaining modeled cost at once:
//  - BLK=256, TPT=2: 8 blocks/CU x 4 waves = full 32 waves/CU (LDS 12.3KB/blk).
//  - rank-0 fast path: ~88% of timesteps are first touches -> emit k0[sk]
//    directly; t/g/s gathers + replay only for rank>0 lanes (exec-masked
//    lanes issue no memory transactions -> ~4x less scattered gather traffic).
//  - coalesced student-row loads hoisted ahead of LDS head-table init.
// If still ~19 us: external floor (graph/launch overhead + latency-bound
// residual) -> roofline.

#define BKT_B 4096
#define BKT_T 512
#define BKT_K 2048
#define BLK   256
#define TPT   (BKT_T / BLK)   // 2 timesteps per thread

__global__ __launch_bounds__(BLK) void bkt_kernel(
    const int* __restrict__ skills,
    const float* __restrict__ resp,
    const float* __restrict__ k0,
    const float* __restrict__ tp,
    const float* __restrict__ gp,
    const float* __restrict__ sp,
    float* __restrict__ out) {
  __shared__ int   nxt_s[BKT_T];    // linked-list next (arbitrary order)
  __shared__ float resp_s[BKT_T];
  __shared__ int   head_s[BKT_K];   // per-skill list head

  const int b = blockIdx.x;
  const int base = b * BKT_T;
  const int tid = threadIdx.x;

  // hoist coalesced loads of this student's row (overlap with head init)
  int   sk[TPT];
  float rr[TPT];
#pragma unroll
  for (int u = 0; u < TPT; ++u) {
    const int t = tid + u * BLK;
    sk[u] = skills[base + t];
    rr[u] = resp[base + t];
  }

  // init head table while loads are in flight
#pragma unroll
  for (int i = 0; i < BKT_K / BLK; ++i)
    head_s[tid + i * BLK] = -1;

#pragma unroll
  for (int u = 0; u < TPT; ++u)
    resp_s[tid + u * BLK] = rr[u];
  __syncthreads();

  // build per-skill linked lists (order irrelevant)
#pragma unroll
  for (int u = 0; u < TPT; ++u) {
    const int t = tid + u * BLK;
    nxt_s[t] = atomicExch(&head_s[sk[u]], t);
  }
  __syncthreads();

#pragma unroll
  for (int u = 0; u < TPT; ++u) {
    const int t = tid + u * BLK;
    const int s_ = sk[u];

    // one walk: count earlier same-skill touches
    const int head = head_s[s_];
    int rank = 0;
    for (int j = head; j >= 0; j = nxt_s[j])
      rank += (j < t);

    float p = k0[s_];                // first-touch prior (rank-0 answer)

    if (rank > 0) {                  // ~12% of lanes: replay prefix in order
      const float ss = sp[s_];
      const float gg = gp[s_];
      const float tt = tp[s_];
      int cur = -1;
      for (int rd = 0; rd < rank; ++rd) {
        int best = INT_MAX;
        for (int j = head; j >= 0; j = nxt_s[j])
          if (j < t && j > cur) best = min(best, j);
        const float r = resp_s[best];
        float num, den;
        if (r > 0.5f) {              // correct response
          num = p * (1.0f - ss);
          den = num + (1.0f - p) * gg;
        } else {                     // incorrect response
          num = p * ss;
          den = num + (1.0f - p) * (1.0f - gg);
        }
        const float q = num / den;   // Bayesian posterior
        p = q + (1.0f - q) * tt;     // learning transition
        cur = best;
      }
    }

    out[base + t] = p;               // emit pre-update mastery
  }
}

extern "C" void kernel_launch(void* const* d_in, const int* in_sizes, int n_in,
                              void* d_out, int out_size, void* d_ws, size_t ws_size,
                              hipStream_t stream) {
  const int*   skills = (const int*)d_in[0];
  const float* resp   = (const float*)d_in[1];
  const float* k0     = (const float*)d_in[2];
  const float* tp     = (const float*)d_in[3];
  const float* gp     = (const float*)d_in[4];
  const float* sp     = (const float*)d_in[5];
  float* out = (float*)d_out;

  bkt_kernel<<<BKT_B, BLK, 0, stream>>>(skills, resp, k0, tp, gp, sp, out);
}